// Round 1
// baseline (1146.111 us; speedup 1.0000x reference)
//
#include <hip/hip_runtime.h>
#include <math.h>

#define NN 100000
#define NE 1600000
#define CIN 128
#define CH  128
#define CO  18

// ---------------- degree / norm ----------------

__global__ __launch_bounds__(256) void k_init_deg(float* __restrict__ deg) {
    int i = blockIdx.x * 256 + threadIdx.x;
    if (i < NN) deg[i] = 1.0f;     // self-loop contributes 1
}

__global__ __launch_bounds__(256) void k_deg(const int* __restrict__ dst,
                                             float* __restrict__ deg) {
    int stride = gridDim.x * 256;
    for (int e = blockIdx.x * 256 + threadIdx.x; e < NE; e += stride)
        atomicAdd(&deg[dst[e]], 1.0f);
}

__global__ __launch_bounds__(256) void k_dinv(const float* __restrict__ deg,
                                              float* __restrict__ dinv) {
    int i = blockIdx.x * 256 + threadIdx.x;
    if (i < NN) dinv[i] = rsqrtf(deg[i]);
}

// ---------------- GEMM1: h1 = x @ W1  (N x 128 @ 128 x 128) ----------------
// 32 rows per 256-thread block. W1 (64KB) + x-rows (16KB) staged in LDS.
// Ws read coalesced across lanes (c consecutive); xs read is wave-broadcast.

__global__ __launch_bounds__(256) void k_gemm1(const float* __restrict__ x,
                                               const float* __restrict__ W,
                                               float* __restrict__ h) {
    __shared__ float Ws[128 * 128];
    __shared__ float xs[32][128];
    int row0 = blockIdx.x * 32;

    for (int i = threadIdx.x; i < 128 * 128; i += 256) Ws[i] = W[i];
    for (int i = threadIdx.x; i < 32 * 128; i += 256) {
        int r = i >> 7, c = i & 127;
        int gr = row0 + r;
        xs[r][c] = (gr < NN) ? x[gr * 128 + c] : 0.0f;
    }
    __syncthreads();

    int c  = threadIdx.x & 127;
    int rh = threadIdx.x >> 7;   // 0 or 1 (uniform per wave)
    float acc[16];
#pragma unroll
    for (int r = 0; r < 16; ++r) acc[r] = 0.0f;

#pragma unroll 4
    for (int k = 0; k < 128; ++k) {
        float wk = Ws[k * 128 + c];
#pragma unroll
        for (int r = 0; r < 16; ++r)
            acc[r] += xs[rh * 16 + r][k] * wk;
    }
#pragma unroll
    for (int r = 0; r < 16; ++r) {
        int gr = row0 + rh * 16 + r;
        if (gr < NN) h[gr * 128 + c] = acc[r];
    }
}

// ---------------- edge scatter, 128-wide ----------------
// 128 lanes per edge (2 edges per 256-thread block slot), grid-stride.

__global__ __launch_bounds__(256) void k_scatter1(const int* __restrict__ src,
                                                  const int* __restrict__ dst,
                                                  const float* __restrict__ dinv,
                                                  const float* __restrict__ h1,
                                                  float* __restrict__ agg) {
    int c = threadIdx.x & 127;
    int eoff = blockIdx.x * 2 + (threadIdx.x >> 7);
    int estride = gridDim.x * 2;
    for (int e = eoff; e < NE; e += estride) {
        int s = src[e], d = dst[e];
        float nrm = dinv[s] * dinv[d];
        atomicAdd(&agg[d * 128 + c], nrm * h1[s * 128 + c]);
    }
}

// ---------------- post1: h1r = relu(agg1 + dinv^2*h1 + b1) (in-place on agg) --

__global__ __launch_bounds__(256) void k_post1(const float* __restrict__ h1,
                                               const float* __restrict__ dinv,
                                               const float* __restrict__ b1,
                                               float* __restrict__ agg) {
    int stride = gridDim.x * 256;
    for (int idx = blockIdx.x * 256 + threadIdx.x; idx < NN * 128; idx += stride) {
        int i = idx >> 7, cc = idx & 127;
        float di = dinv[i];
        float v = agg[idx] + di * di * h1[idx] + b1[cc];
        agg[idx] = fmaxf(v, 0.0f);
    }
}

// ---------------- GEMM2: h2 = h1r @ W2  (N x 128 @ 128 x 18) ----------------
// 128 rows per 256-thread block; rows staged in LDS with +1 pad (stride 129
// -> bank (rl+k)%32, conflict-free); W2 reads are wave-broadcast.

__global__ __launch_bounds__(256) void k_gemm2(const float* __restrict__ h1,
                                               const float* __restrict__ W2,
                                               float* __restrict__ h2) {
    __shared__ float xs[128][129];
    __shared__ float Ws[128 * 18];
    int row0 = blockIdx.x * 128;

    for (int i = threadIdx.x; i < 128 * 18; i += 256) Ws[i] = W2[i];
    for (int i = threadIdx.x; i < 128 * 128; i += 256) {
        int r = i >> 7, c = i & 127;
        int gr = row0 + r;
        xs[r][c] = (gr < NN) ? h1[gr * 128 + c] : 0.0f;
    }
    __syncthreads();

    int rl   = threadIdx.x & 127;
    int half = threadIdx.x >> 7;     // uniform per wave
    int j0   = half * 9;
    float acc[9];
#pragma unroll
    for (int j = 0; j < 9; ++j) acc[j] = 0.0f;

#pragma unroll 4
    for (int k = 0; k < 128; ++k) {
        float xv = xs[rl][k];
#pragma unroll
        for (int j = 0; j < 9; ++j)
            acc[j] += xv * Ws[k * 18 + j0 + j];
    }
    int gr = row0 + rl;
    if (gr < NN) {
#pragma unroll
        for (int j = 0; j < 9; ++j)
            h2[gr * 18 + j0 + j] = acc[j];
    }
}

// ---------------- edge scatter, 18-wide ----------------
// 32-lane group per edge, lanes 0..17 active.

__global__ __launch_bounds__(256) void k_scatter2(const int* __restrict__ src,
                                                  const int* __restrict__ dst,
                                                  const float* __restrict__ dinv,
                                                  const float* __restrict__ h2,
                                                  float* __restrict__ agg2) {
    int g = threadIdx.x >> 5;
    int c = threadIdx.x & 31;
    int eoff = blockIdx.x * 8 + g;
    int estride = gridDim.x * 8;
    for (int e = eoff; e < NE; e += estride) {
        int s = src[e], d = dst[e];
        if (c < CO) {
            float nrm = dinv[s] * dinv[d];
            atomicAdd(&agg2[d * CO + c], nrm * h2[s * CO + c]);
        }
    }
}

// ---------------- post2: log_softmax(agg2 + dinv^2*h2 + b2) ----------------

__global__ __launch_bounds__(256) void k_post2(const float* __restrict__ h2,
                                               const float* __restrict__ agg2,
                                               const float* __restrict__ dinv,
                                               const float* __restrict__ b2,
                                               float* __restrict__ out) {
    int i = blockIdx.x * 256 + threadIdx.x;
    if (i >= NN) return;
    float di = dinv[i];
    float di2 = di * di;
    float v[CO];
    float m = -1e30f;
#pragma unroll
    for (int j = 0; j < CO; ++j) {
        v[j] = agg2[i * CO + j] + di2 * h2[i * CO + j] + b2[j];
        m = fmaxf(m, v[j]);
    }
    float sum = 0.0f;
#pragma unroll
    for (int j = 0; j < CO; ++j) sum += expf(v[j] - m);
    float lse = logf(sum);
#pragma unroll
    for (int j = 0; j < CO; ++j) out[i * CO + j] = v[j] - m - lse;
}

// ---------------- launch ----------------

extern "C" void kernel_launch(void* const* d_in, const int* in_sizes, int n_in,
                              void* d_out, int out_size, void* d_ws, size_t ws_size,
                              hipStream_t stream) {
    const float* x  = (const float*)d_in[0];
    const int*   ei = (const int*)d_in[1];   // [2][E], int32
    const float* W1 = (const float*)d_in[2];
    const float* b1 = (const float*)d_in[3];
    const float* W2 = (const float*)d_in[4];
    const float* b2 = (const float*)d_in[5];
    float* out = (float*)d_out;

    const int* src = ei;
    const int* dst = ei + NE;

    // workspace layout (floats)
    float* ws   = (float*)d_ws;
    float* h1   = ws;                         // N*128
    float* agg1 = h1 + (size_t)NN * CH;       // N*128 (becomes relu'd h1r in place)
    float* h2   = agg1 + (size_t)NN * CH;     // N*18
    float* agg2 = h2 + (size_t)NN * CO;       // N*18
    float* deg  = agg2 + (size_t)NN * CO;     // N
    float* dinv = deg + NN;                   // N

    hipMemsetAsync(agg1, 0, (size_t)NN * CH * sizeof(float), stream);
    hipMemsetAsync(agg2, 0, (size_t)NN * CO * sizeof(float), stream);

    k_init_deg<<<(NN + 255) / 256, 256, 0, stream>>>(deg);
    k_deg<<<2048, 256, 0, stream>>>(dst, deg);
    k_dinv<<<(NN + 255) / 256, 256, 0, stream>>>(deg, dinv);

    k_gemm1<<<(NN + 31) / 32, 256, 0, stream>>>(x, W1, h1);
    k_scatter1<<<4096, 256, 0, stream>>>(src, dst, dinv, h1, agg1);
    k_post1<<<4096, 256, 0, stream>>>(h1, dinv, b1, agg1);

    k_gemm2<<<(NN + 127) / 128, 256, 0, stream>>>(agg1, W2, h2);
    k_scatter2<<<4096, 256, 0, stream>>>(src, dst, dinv, h2, agg2);
    k_post2<<<(NN + 255) / 256, 256, 0, stream>>>(h2, agg2, dinv, b2, out);
}

// Round 2
// 563.579 us; speedup vs baseline: 2.0336x; 2.0336x over previous
//
#include <hip/hip_runtime.h>
#include <math.h>

#define NN 100000
#define NE 1600000
#define CIN 128
#define CH  128
#define CO  18
#define NB  ((NN + 255) / 256)   // 391

// ---------------- CSR build ----------------

__global__ __launch_bounds__(256) void k_count(const int* __restrict__ dst,
                                               int* __restrict__ counts) {
    int stride = gridDim.x * 256;
    for (int e = blockIdx.x * 256 + threadIdx.x; e < NE; e += stride)
        atomicAdd(&counts[dst[e]], 1);
}

__global__ __launch_bounds__(256) void k_dinv(const int* __restrict__ counts,
                                              float* __restrict__ dinv) {
    int i = blockIdx.x * 256 + threadIdx.x;
    if (i < NN) dinv[i] = rsqrtf((float)counts[i] + 1.0f);  // +1 self-loop
}

// block-level exclusive scan (Hillis-Steele in LDS)
__global__ __launch_bounds__(256) void k_scan1(const int* __restrict__ counts,
                                               int* __restrict__ row_start,
                                               int* __restrict__ bsum) {
    __shared__ int s[256];
    int tid = threadIdx.x;
    int i = blockIdx.x * 256 + tid;
    int c = (i < NN) ? counts[i] : 0;
    s[tid] = c;
    __syncthreads();
    for (int off = 1; off < 256; off <<= 1) {
        int t = (tid >= off) ? s[tid - off] : 0;
        __syncthreads();
        s[tid] += t;
        __syncthreads();
    }
    if (i < NN) row_start[i] = s[tid] - c;          // exclusive within block
    if (tid == 255) bsum[blockIdx.x] = s[255];      // block total
}

__global__ __launch_bounds__(512) void k_scan2(int* __restrict__ bsum) {
    __shared__ int s[512];
    int tid = threadIdx.x;
    int c = (tid < NB) ? bsum[tid] : 0;
    s[tid] = c;
    __syncthreads();
    for (int off = 1; off < 512; off <<= 1) {
        int t = (tid >= off) ? s[tid - off] : 0;
        __syncthreads();
        s[tid] += t;
        __syncthreads();
    }
    if (tid < NB) bsum[tid] = s[tid] - c;           // exclusive block base
}

__global__ __launch_bounds__(256) void k_scan3(int* __restrict__ row_start,
                                               const int* __restrict__ bsum,
                                               int* __restrict__ cursor) {
    int i = blockIdx.x * 256 + threadIdx.x;
    if (i < NN) {
        int v = row_start[i] + bsum[blockIdx.x];
        row_start[i] = v;
        cursor[i] = v;
    }
    if (i == NN) row_start[NN] = NE;
}

__global__ __launch_bounds__(256) void k_fill(const int* __restrict__ src,
                                              const int* __restrict__ dst,
                                              int* __restrict__ cursor,
                                              int* __restrict__ csr_src) {
    int stride = gridDim.x * 256;
    for (int e = blockIdx.x * 256 + threadIdx.x; e < NE; e += stride) {
        int d = dst[e];
        int pos = atomicAdd(&cursor[d], 1);
        csr_src[pos] = src[e];
    }
}

// ---------------- GEMM1: h1 = x @ W1  (N x 128 @ 128 x 128) ----------------

__global__ __launch_bounds__(256) void k_gemm1(const float* __restrict__ x,
                                               const float* __restrict__ W,
                                               float* __restrict__ h) {
    __shared__ float Ws[128 * 128];
    __shared__ float xs[32][128];
    int row0 = blockIdx.x * 32;

    for (int i = threadIdx.x; i < 128 * 128; i += 256) Ws[i] = W[i];
    for (int i = threadIdx.x; i < 32 * 128; i += 256) {
        int r = i >> 7, c = i & 127;
        int gr = row0 + r;
        xs[r][c] = (gr < NN) ? x[gr * 128 + c] : 0.0f;
    }
    __syncthreads();

    int c  = threadIdx.x & 127;
    int rh = threadIdx.x >> 7;
    float acc[16];
#pragma unroll
    for (int r = 0; r < 16; ++r) acc[r] = 0.0f;

#pragma unroll 4
    for (int k = 0; k < 128; ++k) {
        float wk = Ws[k * 128 + c];
#pragma unroll
        for (int r = 0; r < 16; ++r)
            acc[r] += xs[rh * 16 + r][k] * wk;
    }
#pragma unroll
    for (int r = 0; r < 16; ++r) {
        int gr = row0 + rh * 16 + r;
        if (gr < NN) h[gr * 128 + c] = acc[r];
    }
}

// ---------------- agg1 (CSR gather) + bias + relu, one wave per node --------

__global__ __launch_bounds__(256) void k_agg1(const int* __restrict__ row_start,
                                              const int* __restrict__ csr_src,
                                              const float* __restrict__ dinv,
                                              const float* __restrict__ h1,
                                              const float* __restrict__ b1,
                                              float* __restrict__ h1r) {
    int wave = threadIdx.x >> 6;
    int lane = threadIdx.x & 63;
    int i = blockIdx.x * 4 + wave;
    if (i >= NN) return;
    int r0 = row_start[i], r1 = row_start[i + 1];
    float di = dinv[i];
    const float2* h1v = (const float2*)h1;
    float ax = 0.0f, ay = 0.0f;

    int j = r0;
    for (; j + 1 < r1; j += 2) {      // 2-edge unroll: independent load chains
        int s0 = csr_src[j], s1 = csr_src[j + 1];
        float w0 = dinv[s0] * di;
        float w1 = dinv[s1] * di;
        float2 a0 = h1v[(size_t)s0 * 64 + lane];
        float2 a1 = h1v[(size_t)s1 * 64 + lane];
        ax += w0 * a0.x + w1 * a1.x;
        ay += w0 * a0.y + w1 * a1.y;
    }
    if (j < r1) {
        int s0 = csr_src[j];
        float w0 = dinv[s0] * di;
        float2 a0 = h1v[(size_t)s0 * 64 + lane];
        ax += w0 * a0.x;
        ay += w0 * a0.y;
    }

    float2 hv = h1v[(size_t)i * 64 + lane];
    float2 bb = ((const float2*)b1)[lane];
    float di2 = di * di;
    float2 o;
    o.x = fmaxf(ax + di2 * hv.x + bb.x, 0.0f);
    o.y = fmaxf(ay + di2 * hv.y + bb.y, 0.0f);
    ((float2*)h1r)[(size_t)i * 64 + lane] = o;
}

// ---------------- GEMM2: h2 = h1r @ W2  (N x 128 @ 128 x 18) ----------------

__global__ __launch_bounds__(256) void k_gemm2(const float* __restrict__ h1,
                                               const float* __restrict__ W2,
                                               float* __restrict__ h2) {
    __shared__ float xs[128][129];
    __shared__ float Ws[128 * 18];
    int row0 = blockIdx.x * 128;

    for (int i = threadIdx.x; i < 128 * 18; i += 256) Ws[i] = W2[i];
    for (int i = threadIdx.x; i < 128 * 128; i += 256) {
        int r = i >> 7, c = i & 127;
        int gr = row0 + r;
        xs[r][c] = (gr < NN) ? h1[gr * 128 + c] : 0.0f;
    }
    __syncthreads();

    int rl   = threadIdx.x & 127;
    int half = threadIdx.x >> 7;
    int j0   = half * 9;
    float acc[9];
#pragma unroll
    for (int j = 0; j < 9; ++j) acc[j] = 0.0f;

#pragma unroll 4
    for (int k = 0; k < 128; ++k) {
        float xv = xs[rl][k];
#pragma unroll
        for (int j = 0; j < 9; ++j)
            acc[j] += xv * Ws[k * 18 + j0 + j];
    }
    int gr = row0 + rl;
    if (gr < NN) {
#pragma unroll
        for (int j = 0; j < 9; ++j)
            h2[gr * 18 + j0 + j] = acc[j];
    }
}

// ------- agg2 (CSR gather) + bias + self-loop + log_softmax, 1 thread/node --

__global__ __launch_bounds__(256) void k_agg2(const int* __restrict__ row_start,
                                              const int* __restrict__ csr_src,
                                              const float* __restrict__ dinv,
                                              const float* __restrict__ h2,
                                              const float* __restrict__ b2,
                                              float* __restrict__ out) {
    int i = blockIdx.x * 256 + threadIdx.x;
    if (i >= NN) return;
    int r0 = row_start[i], r1 = row_start[i + 1];
    float di = dinv[i];
    float acc[CO];
#pragma unroll
    for (int j = 0; j < CO; ++j) acc[j] = 0.0f;

    for (int e = r0; e < r1; ++e) {
        int s = csr_src[e];
        float w = dinv[s] * di;
        const float* hr = h2 + (size_t)s * CO;
#pragma unroll
        for (int j = 0; j < CO; ++j) acc[j] += w * hr[j];
    }

    float di2 = di * di;
    const float* hi = h2 + (size_t)i * CO;
    float m = -1e30f;
#pragma unroll
    for (int j = 0; j < CO; ++j) {
        acc[j] = acc[j] + di2 * hi[j] + b2[j];
        m = fmaxf(m, acc[j]);
    }
    float sum = 0.0f;
#pragma unroll
    for (int j = 0; j < CO; ++j) sum += expf(acc[j] - m);
    float lse = logf(sum);
    float* op = out + (size_t)i * CO;
#pragma unroll
    for (int j = 0; j < CO; ++j) op[j] = acc[j] - m - lse;
}

// ---------------- launch ----------------

extern "C" void kernel_launch(void* const* d_in, const int* in_sizes, int n_in,
                              void* d_out, int out_size, void* d_ws, size_t ws_size,
                              hipStream_t stream) {
    const float* x  = (const float*)d_in[0];
    const int*   ei = (const int*)d_in[1];
    const float* W1 = (const float*)d_in[2];
    const float* b1 = (const float*)d_in[3];
    const float* W2 = (const float*)d_in[4];
    const float* b2 = (const float*)d_in[5];
    float* out = (float*)d_out;

    const int* src = ei;
    const int* dst = ei + NE;

    // workspace layout (117.2 MB, within previous 117.6 MB footprint)
    float* h1   = (float*)d_ws;                       // N*128
    float* h1r  = h1 + (size_t)NN * CH;               // N*128
    float* h2   = h1r + (size_t)NN * CH;              // N*18
    float* dinv = h2 + (size_t)NN * CO;               // N
    int* counts    = (int*)(dinv + NN);               // N   (reused as cursor)
    int* row_start = counts + NN;                     // N+1
    int* csr_src   = row_start + NN + 1;              // E
    int* bsum      = csr_src + NE;                    // 512

    hipMemsetAsync(counts, 0, (size_t)NN * sizeof(int), stream);

    k_count<<<2048, 256, 0, stream>>>(dst, counts);
    k_dinv<<<NB, 256, 0, stream>>>(counts, dinv);
    k_scan1<<<NB, 256, 0, stream>>>(counts, row_start, bsum);
    k_scan2<<<1, 512, 0, stream>>>(bsum);
    k_scan3<<<NB, 256, 0, stream>>>(row_start, bsum, counts /*cursor*/);
    k_fill<<<2048, 256, 0, stream>>>(src, dst, counts /*cursor*/, csr_src);

    k_gemm1<<<(NN + 31) / 32, 256, 0, stream>>>(x, W1, h1);
    k_agg1<<<(NN + 3) / 4, 256, 0, stream>>>(row_start, csr_src, dinv, h1, b1, h1r);
    k_gemm2<<<(NN + 127) / 128, 256, 0, stream>>>(h1r, W2, h2);
    k_agg2<<<NB, 256, 0, stream>>>(row_start, csr_src, dinv, h2, b2, out);
}

// Round 3
// 472.136 us; speedup vs baseline: 2.4275x; 1.1937x over previous
//
#include <hip/hip_runtime.h>
#include <math.h>

#define NN 100000
#define NE 1600000
#define CIN 128
#define CH  128
#define CO  18
#define NB  ((NN + 255) / 256)   // 391

typedef unsigned int uint;
typedef unsigned short ushort;

// ---- bf16 helpers (packed pairs in uint) ----
__device__ __forceinline__ float bf_lo(uint u) { return __uint_as_float(u << 16); }
__device__ __forceinline__ float bf_hi(uint u) { return __uint_as_float(u & 0xFFFF0000u); }
__device__ __forceinline__ uint pack_bf16(float a, float b) {
    uint ua = __float_as_uint(a), ub = __float_as_uint(b);
    ua += 0x7FFFu + ((ua >> 16) & 1u);      // RNE
    ub += 0x7FFFu + ((ub >> 16) & 1u);
    return (ua >> 16) | (ub & 0xFFFF0000u);
}

// ---------------- CSR build ----------------

__global__ __launch_bounds__(256) void k_count(const int* __restrict__ dst,
                                               int* __restrict__ counts) {
    int stride = gridDim.x * 256;
    for (int e = blockIdx.x * 256 + threadIdx.x; e < NE; e += stride)
        atomicAdd(&counts[dst[e]], 1);
}

__global__ __launch_bounds__(256) void k_dinv(const int* __restrict__ counts,
                                              float* __restrict__ dinv) {
    int i = blockIdx.x * 256 + threadIdx.x;
    if (i < NN) dinv[i] = rsqrtf((float)counts[i] + 1.0f);  // +1 self-loop
}

__global__ __launch_bounds__(256) void k_scan1(const int* __restrict__ counts,
                                               int* __restrict__ row_start,
                                               int* __restrict__ bsum) {
    __shared__ int s[256];
    int tid = threadIdx.x;
    int i = blockIdx.x * 256 + tid;
    int c = (i < NN) ? counts[i] : 0;
    s[tid] = c;
    __syncthreads();
    for (int off = 1; off < 256; off <<= 1) {
        int t = (tid >= off) ? s[tid - off] : 0;
        __syncthreads();
        s[tid] += t;
        __syncthreads();
    }
    if (i < NN) row_start[i] = s[tid] - c;
    if (tid == 255) bsum[blockIdx.x] = s[255];
}

__global__ __launch_bounds__(512) void k_scan2(int* __restrict__ bsum) {
    __shared__ int s[512];
    int tid = threadIdx.x;
    int c = (tid < NB) ? bsum[tid] : 0;
    s[tid] = c;
    __syncthreads();
    for (int off = 1; off < 512; off <<= 1) {
        int t = (tid >= off) ? s[tid - off] : 0;
        __syncthreads();
        s[tid] += t;
        __syncthreads();
    }
    if (tid < NB) bsum[tid] = s[tid] - c;
}

__global__ __launch_bounds__(256) void k_scan3(int* __restrict__ row_start,
                                               const int* __restrict__ bsum,
                                               int* __restrict__ cursor) {
    int i = blockIdx.x * 256 + threadIdx.x;
    if (i < NN) {
        int v = row_start[i] + bsum[blockIdx.x];
        row_start[i] = v;
        cursor[i] = v;
    }
    if (i == NN) row_start[NN] = NE;
}

__global__ __launch_bounds__(256) void k_fill(const int* __restrict__ src,
                                              const int* __restrict__ dst,
                                              int* __restrict__ cursor,
                                              int* __restrict__ csr_src) {
    int stride = gridDim.x * 256;
    for (int e = blockIdx.x * 256 + threadIdx.x; e < NE; e += stride) {
        int d = dst[e];
        int pos = atomicAdd(&cursor[d], 1);
        csr_src[pos] = src[e];
    }
}

// ------- GEMM1: h1b(bf16) = x @ W1 ; reg-tiled 4 rows x 8 cols/thread -------
// LDS: xs fp32 [64][132] (33KB) + W1 packed bf16 uint[128][64] (32KB) = 65KB
// -> 2 blocks/CU. Per k: 4 xs b32 (2-way=free) + 4 W uint b32 -> 32 FMA.

__global__ __launch_bounds__(256, 2) void k_gemm1(const float* __restrict__ x,
                                                  const float* __restrict__ W,
                                                  uint* __restrict__ h1u) {
    __shared__ float xs[64][132];
    __shared__ uint  Wsb[128 * 64];
    int row0 = blockIdx.x * 64;
    int tid = threadIdx.x;

    // stage W1 as packed bf16 (layout uint[k][cu]: cols {2cu,2cu+1})
    const float2* Wv = (const float2*)W;
    for (int p = tid; p < 128 * 64; p += 256) {
        float2 wv = Wv[p];
        Wsb[p] = pack_bf16(wv.x, wv.y);
    }
    // stage x rows fp32
    for (int i = tid; i < 64 * 128; i += 256) {
        int r = i >> 7, c = i & 127;
        int gr = row0 + r;
        xs[r][c] = (gr < NN) ? x[(size_t)gr * 128 + c] : 0.0f;
    }
    __syncthreads();

    int cg = tid & 15;        // uint-col group: cols cg+16j, j=0..3
    int rg = tid >> 4;        // row group: rows rg*4..rg*4+3
    float acc[4][8];
#pragma unroll
    for (int i = 0; i < 4; ++i)
#pragma unroll
        for (int j = 0; j < 8; ++j) acc[i][j] = 0.0f;

#pragma unroll 4
    for (int k = 0; k < 128; ++k) {
        float xv[4];
#pragma unroll
        for (int i = 0; i < 4; ++i) xv[i] = xs[rg * 4 + i][k];
#pragma unroll
        for (int j = 0; j < 4; ++j) {
            uint w = Wsb[k * 64 + cg + 16 * j];
            float w0 = bf_lo(w), w1 = bf_hi(w);
#pragma unroll
            for (int i = 0; i < 4; ++i) {
                acc[i][2 * j]     += xv[i] * w0;
                acc[i][2 * j + 1] += xv[i] * w1;
            }
        }
    }
#pragma unroll
    for (int i = 0; i < 4; ++i) {
        int gr = row0 + rg * 4 + i;
        if (gr < NN) {
#pragma unroll
            for (int j = 0; j < 4; ++j)
                h1u[(size_t)gr * 64 + cg + 16 * j] = pack_bf16(acc[i][2 * j], acc[i][2 * j + 1]);
        }
    }
}

// ------- agg1 (CSR gather, bf16 rows) + self-loop + bias + relu -> bf16 -----

__global__ __launch_bounds__(256) void k_agg1(const int* __restrict__ row_start,
                                              const int* __restrict__ csr_src,
                                              const float* __restrict__ dinv,
                                              const uint* __restrict__ h1u,
                                              const float* __restrict__ b1,
                                              uint* __restrict__ h1ru) {
    int wave = threadIdx.x >> 6;
    int lane = threadIdx.x & 63;
    int i = blockIdx.x * 4 + wave;
    if (i >= NN) return;
    int r0 = row_start[i], r1 = row_start[i + 1];
    float di = dinv[i];
    float ax = 0.0f, ay = 0.0f;

    int j = r0;
    for (; j + 1 < r1; j += 2) {
        int s0 = csr_src[j], s1 = csr_src[j + 1];
        float w0 = dinv[s0] * di;
        float w1 = dinv[s1] * di;
        uint u0 = h1u[(size_t)s0 * 64 + lane];
        uint u1 = h1u[(size_t)s1 * 64 + lane];
        ax += w0 * bf_lo(u0) + w1 * bf_lo(u1);
        ay += w0 * bf_hi(u0) + w1 * bf_hi(u1);
    }
    if (j < r1) {
        int s0 = csr_src[j];
        float w0 = dinv[s0] * di;
        uint u0 = h1u[(size_t)s0 * 64 + lane];
        ax += w0 * bf_lo(u0);
        ay += w0 * bf_hi(u0);
    }

    uint us = h1u[(size_t)i * 64 + lane];
    float2 bb = ((const float2*)b1)[lane];
    float di2 = di * di;
    float ox = fmaxf(ax + di2 * bf_lo(us) + bb.x, 0.0f);
    float oy = fmaxf(ay + di2 * bf_hi(us) + bb.y, 0.0f);
    h1ru[(size_t)i * 64 + lane] = pack_bf16(ox, oy);
}

// ------- GEMM2: h2b(bf16) = h1r(bf16) @ W2 ----------------------------------
// stage h1r rows as fp32 [128][129] (conflict-free), W2 fp32 in LDS.

__global__ __launch_bounds__(256, 2) void k_gemm2(const uint* __restrict__ h1ru,
                                                  const float* __restrict__ W2,
                                                  ushort* __restrict__ h2b) {
    __shared__ float xs[128][129];
    __shared__ float Ws[128 * 18];
    int row0 = blockIdx.x * 128;
    int tid = threadIdx.x;

    for (int i = tid; i < 128 * 18; i += 256) Ws[i] = W2[i];
    for (int i = tid; i < 128 * 64; i += 256) {
        int r = i >> 6, c2 = i & 63;
        int gr = row0 + r;
        uint u = (gr < NN) ? h1ru[(size_t)gr * 64 + c2] : 0u;
        xs[r][2 * c2]     = bf_lo(u);
        xs[r][2 * c2 + 1] = bf_hi(u);
    }
    __syncthreads();

    int rl   = tid & 127;
    int half = tid >> 7;
    int j0   = half * 9;
    float acc[9];
#pragma unroll
    for (int j = 0; j < 9; ++j) acc[j] = 0.0f;

#pragma unroll 4
    for (int k = 0; k < 128; ++k) {
        float xv = xs[rl][k];
#pragma unroll
        for (int j = 0; j < 9; ++j)
            acc[j] += xv * Ws[k * 18 + j0 + j];
    }
    int gr = row0 + rl;
    if (gr < NN) {
#pragma unroll
        for (int j = 0; j < 9; ++j) {
            uint ua = __float_as_uint(acc[j]);
            ua += 0x7FFFu + ((ua >> 16) & 1u);
            h2b[(size_t)gr * 18 + j0 + j] = (ushort)(ua >> 16);
        }
    }
}

// ------- agg2 (CSR gather, bf16) + self-loop + bias + log_softmax -----------

__global__ __launch_bounds__(256) void k_agg2(const int* __restrict__ row_start,
                                              const int* __restrict__ csr_src,
                                              const float* __restrict__ dinv,
                                              const uint* __restrict__ h2u,   // 9 uints/row
                                              const float* __restrict__ b2,
                                              float* __restrict__ out) {
    int i = blockIdx.x * 256 + threadIdx.x;
    if (i >= NN) return;
    int r0 = row_start[i], r1 = row_start[i + 1];
    float di = dinv[i];
    float acc[CO];
#pragma unroll
    for (int j = 0; j < CO; ++j) acc[j] = 0.0f;

    for (int e = r0; e < r1; ++e) {
        int s = csr_src[e];
        float w = dinv[s] * di;
        const uint* hr = h2u + (size_t)s * 9;
#pragma unroll
        for (int j = 0; j < 9; ++j) {
            uint u = hr[j];
            acc[2 * j]     += w * bf_lo(u);
            acc[2 * j + 1] += w * bf_hi(u);
        }
    }

    float di2 = di * di;
    const uint* hi = h2u + (size_t)i * 9;
    float m = -1e30f;
#pragma unroll
    for (int j = 0; j < 9; ++j) {
        uint u = hi[j];
        acc[2 * j]     += di2 * bf_lo(u) + b2[2 * j];
        acc[2 * j + 1] += di2 * bf_hi(u) + b2[2 * j + 1];
    }
#pragma unroll
    for (int j = 0; j < CO; ++j) m = fmaxf(m, acc[j]);
    float sum = 0.0f;
#pragma unroll
    for (int j = 0; j < CO; ++j) sum += expf(acc[j] - m);
    float lse = logf(sum);
    float* op = out + (size_t)i * CO;
#pragma unroll
    for (int j = 0; j < CO; ++j) op[j] = acc[j] - m - lse;
}

// ---------------- launch ----------------

extern "C" void kernel_launch(void* const* d_in, const int* in_sizes, int n_in,
                              void* d_out, int out_size, void* d_ws, size_t ws_size,
                              hipStream_t stream) {
    const float* x  = (const float*)d_in[0];
    const int*   ei = (const int*)d_in[1];
    const float* W1 = (const float*)d_in[2];
    const float* b1 = (const float*)d_in[3];
    const float* W2 = (const float*)d_in[4];
    const float* b2 = (const float*)d_in[5];
    float* out = (float*)d_out;

    const int* src = ei;
    const int* dst = ei + NE;

    // workspace layout (~62 MB)
    uint* h1u  = (uint*)d_ws;                        // N*64 uints (bf16 pairs)
    uint* h1ru = h1u + (size_t)NN * 64;              // N*64 uints
    uint* h2u  = h1ru + (size_t)NN * 64;             // N*9 uints (18 bf16)
    float* dinv = (float*)(h2u + (size_t)NN * 9);    // N
    int* counts    = (int*)(dinv + NN);              // N (reused as cursor)
    int* row_start = counts + NN;                    // N+1
    int* csr_src   = row_start + NN + 1;             // E
    int* bsum      = csr_src + NE;                   // 512

    hipMemsetAsync(counts, 0, (size_t)NN * sizeof(int), stream);

    k_count<<<2048, 256, 0, stream>>>(dst, counts);
    k_dinv<<<NB, 256, 0, stream>>>(counts, dinv);
    k_scan1<<<NB, 256, 0, stream>>>(counts, row_start, bsum);
    k_scan2<<<1, 512, 0, stream>>>(bsum);
    k_scan3<<<NB, 256, 0, stream>>>(row_start, bsum, counts /*cursor*/);
    k_fill<<<2048, 256, 0, stream>>>(src, dst, counts /*cursor*/, csr_src);

    k_gemm1<<<(NN + 63) / 64, 256, 0, stream>>>(x, W1, h1u);
    k_agg1<<<(NN + 3) / 4, 256, 0, stream>>>(row_start, csr_src, dinv, h1u, b1, h1ru);
    k_gemm2<<<(NN + 127) / 128, 256, 0, stream>>>(h1ru, W2, (ushort*)h2u);
    k_agg2<<<NB, 256, 0, stream>>>(row_start, csr_src, dinv, h2u, b2, out);
}

// Round 4
// 337.697 us; speedup vs baseline: 3.3939x; 1.3981x over previous
//
#include <hip/hip_runtime.h>
#include <math.h>

#define NN 100000
#define NE 1600000
#define CH  128
#define CO  18
#define NPB 256                        // nodes per bucket (dst >> 8)
#define NBUK ((NN + NPB - 1) / NPB)    // 391
#define EPB 4096                       // edges per k_bin block
#define NBB ((NE + EPB - 1) / EPB)     // 391

typedef unsigned int uint;
typedef unsigned short ushort;

// ---- bf16 helpers (packed pairs in uint) ----
__device__ __forceinline__ float bf_lo(uint u) { return __uint_as_float(u << 16); }
__device__ __forceinline__ float bf_hi(uint u) { return __uint_as_float(u & 0xFFFF0000u); }
__device__ __forceinline__ uint pack_bf16(float a, float b) {
    uint ua = __float_as_uint(a), ub = __float_as_uint(b);
    ua += 0x7FFFu + ((ua >> 16) & 1u);      // RNE
    ub += 0x7FFFu + ((ub >> 16) & 1u);
    return (ua >> 16) | (ub & 0xFFFF0000u);
}

// ---------------- binned CSR build ----------------

// 1) bucket histogram: LDS hist per block, one global atomic per nonzero slot
__global__ __launch_bounds__(256) void k_bhist(const int* __restrict__ dst,
                                               int* __restrict__ bcnt) {
    __shared__ int h[NBUK];
    int tid = threadIdx.x;
    for (int i = tid; i < NBUK; i += 256) h[i] = 0;
    __syncthreads();
    int e0 = blockIdx.x * EPB;
#pragma unroll
    for (int i = 0; i < EPB / 256; ++i) {
        int e = e0 + i * 256 + tid;
        if (e < NE) atomicAdd(&h[dst[e] >> 8], 1);
    }
    __syncthreads();
    for (int i = tid; i < NBUK; i += 256)
        if (h[i]) atomicAdd(&bcnt[i], h[i]);
}

// 2) scan buckets -> bucket_base[0..NBUK], and init global cursors
__global__ __launch_bounds__(512) void k_bscan(const int* __restrict__ bcnt,
                                               int* __restrict__ bbase,
                                               int* __restrict__ bcur) {
    __shared__ int s[512];
    int tid = threadIdx.x;
    int c = (tid < NBUK) ? bcnt[tid] : 0;
    s[tid] = c;
    __syncthreads();
    for (int off = 1; off < 512; off <<= 1) {
        int t = (tid >= off) ? s[tid - off] : 0;
        __syncthreads();
        s[tid] += t;
        __syncthreads();
    }
    if (tid < NBUK) {
        int ex = s[tid] - c;
        bbase[tid] = ex;
        bcur[tid] = ex;
    }
    if (tid == NBUK) bbase[NBUK] = NE;
}

// 3) bin edges into bucket regions as (src,dst) records; edges held in regs
__global__ __launch_bounds__(256) void k_bin(const int* __restrict__ src,
                                             const int* __restrict__ dst,
                                             int* __restrict__ bcur,
                                             uint2* __restrict__ etmp) {
    __shared__ int h[NBUK];
    __shared__ int base[NBUK];
    int tid = threadIdx.x;
    for (int i = tid; i < NBUK; i += 256) h[i] = 0;
    __syncthreads();

    int e0 = blockIdx.x * EPB;
    int sv[EPB / 256], dv[EPB / 256];
#pragma unroll
    for (int i = 0; i < EPB / 256; ++i) {
        int e = e0 + i * 256 + tid;
        if (e < NE) {
            sv[i] = src[e];
            dv[i] = dst[e];
            atomicAdd(&h[dv[i] >> 8], 1);
        } else {
            dv[i] = -1;
        }
    }
    __syncthreads();
    // reserve space per bucket
    for (int i = tid; i < NBUK; i += 256)
        base[i] = h[i] ? atomicAdd(&bcur[i], h[i]) : 0;
    __syncthreads();
    // reuse h as local cursor
    for (int i = tid; i < NBUK; i += 256) h[i] = 0;
    __syncthreads();
#pragma unroll
    for (int i = 0; i < EPB / 256; ++i) {
        if (dv[i] >= 0) {
            int b = dv[i] >> 8;
            int pos = base[b] + atomicAdd(&h[b], 1);
            etmp[pos] = make_uint2((uint)sv[i], (uint)dv[i]);
        }
    }
}

// 4) per bucket: node histogram + scan -> row_start, dinv, distribute csr_src
__global__ __launch_bounds__(256) void k_pass2(const int* __restrict__ bbase,
                                               const uint2* __restrict__ etmp,
                                               int* __restrict__ row_start,
                                               float* __restrict__ dinv,
                                               int* __restrict__ csr_src) {
    __shared__ int hist[NPB];
    __shared__ int s[NPB];
    __shared__ int cur[NPB];
    int tid = threadIdx.x;
    int b = blockIdx.x;
    int e0 = bbase[b], e1 = bbase[b + 1];

    hist[tid] = 0;
    __syncthreads();
    for (int e = e0 + tid; e < e1; e += 256)
        atomicAdd(&hist[etmp[e].y & 255], 1);
    __syncthreads();

    int c = hist[tid];
    s[tid] = c;
    __syncthreads();
    for (int off = 1; off < 256; off <<= 1) {
        int t = (tid >= off) ? s[tid - off] : 0;
        __syncthreads();
        s[tid] += t;
        __syncthreads();
    }
    int pfx = s[tid] - c;          // exclusive prefix within bucket
    s[tid] = pfx;                  // keep for phase C
    cur[tid] = 0;

    int node = b * NPB + tid;
    if (node < NN) {
        row_start[node] = e0 + pfx;
        dinv[node] = rsqrtf((float)c + 1.0f);   // +1 self-loop
    }
    if (b == NBUK - 1 && tid == 0) row_start[NN] = NE;
    __syncthreads();

    for (int e = e0 + tid; e < e1; e += 256) {
        uint2 r = etmp[e];
        int n = r.y & 255;
        int p = e0 + s[n] + atomicAdd(&cur[n], 1);
        csr_src[p] = (int)r.x;
    }
}

// ------- GEMM1: h1b(bf16) = x @ W1 ; reg-tiled 4 rows x 8 cols/thread -------

__global__ __launch_bounds__(256, 2) void k_gemm1(const float* __restrict__ x,
                                                  const float* __restrict__ W,
                                                  uint* __restrict__ h1u) {
    __shared__ float xs[64][132];
    __shared__ uint  Wsb[128 * 64];
    int row0 = blockIdx.x * 64;
    int tid = threadIdx.x;

    const float2* Wv = (const float2*)W;
    for (int p = tid; p < 128 * 64; p += 256) {
        float2 wv = Wv[p];
        Wsb[p] = pack_bf16(wv.x, wv.y);
    }
    for (int i = tid; i < 64 * 128; i += 256) {
        int r = i >> 7, c = i & 127;
        int gr = row0 + r;
        xs[r][c] = (gr < NN) ? x[(size_t)gr * 128 + c] : 0.0f;
    }
    __syncthreads();

    int cg = tid & 15;
    int rg = tid >> 4;
    float acc[4][8];
#pragma unroll
    for (int i = 0; i < 4; ++i)
#pragma unroll
        for (int j = 0; j < 8; ++j) acc[i][j] = 0.0f;

#pragma unroll 4
    for (int k = 0; k < 128; ++k) {
        float xv[4];
#pragma unroll
        for (int i = 0; i < 4; ++i) xv[i] = xs[rg * 4 + i][k];
#pragma unroll
        for (int j = 0; j < 4; ++j) {
            uint w = Wsb[k * 64 + cg + 16 * j];
            float w0 = bf_lo(w), w1 = bf_hi(w);
#pragma unroll
            for (int i = 0; i < 4; ++i) {
                acc[i][2 * j]     += xv[i] * w0;
                acc[i][2 * j + 1] += xv[i] * w1;
            }
        }
    }
#pragma unroll
    for (int i = 0; i < 4; ++i) {
        int gr = row0 + rg * 4 + i;
        if (gr < NN) {
#pragma unroll
            for (int j = 0; j < 4; ++j)
                h1u[(size_t)gr * 64 + cg + 16 * j] = pack_bf16(acc[i][2 * j], acc[i][2 * j + 1]);
        }
    }
}

// ------- agg1 (CSR gather, bf16 rows) + self-loop + bias + relu -> bf16 -----

__global__ __launch_bounds__(256) void k_agg1(const int* __restrict__ row_start,
                                              const int* __restrict__ csr_src,
                                              const float* __restrict__ dinv,
                                              const uint* __restrict__ h1u,
                                              const float* __restrict__ b1,
                                              uint* __restrict__ h1ru) {
    int wave = threadIdx.x >> 6;
    int lane = threadIdx.x & 63;
    int i = blockIdx.x * 4 + wave;
    if (i >= NN) return;
    int r0 = row_start[i], r1 = row_start[i + 1];
    float di = dinv[i];
    float ax = 0.0f, ay = 0.0f;

    int j = r0;
    for (; j + 1 < r1; j += 2) {
        int s0 = csr_src[j], s1 = csr_src[j + 1];
        float w0 = dinv[s0] * di;
        float w1 = dinv[s1] * di;
        uint u0 = h1u[(size_t)s0 * 64 + lane];
        uint u1 = h1u[(size_t)s1 * 64 + lane];
        ax += w0 * bf_lo(u0) + w1 * bf_lo(u1);
        ay += w0 * bf_hi(u0) + w1 * bf_hi(u1);
    }
    if (j < r1) {
        int s0 = csr_src[j];
        float w0 = dinv[s0] * di;
        uint u0 = h1u[(size_t)s0 * 64 + lane];
        ax += w0 * bf_lo(u0);
        ay += w0 * bf_hi(u0);
    }

    uint us = h1u[(size_t)i * 64 + lane];
    float2 bb = ((const float2*)b1)[lane];
    float di2 = di * di;
    float ox = fmaxf(ax + di2 * bf_lo(us) + bb.x, 0.0f);
    float oy = fmaxf(ay + di2 * bf_hi(us) + bb.y, 0.0f);
    h1ru[(size_t)i * 64 + lane] = pack_bf16(ox, oy);
}

// ------- GEMM2: h2b(bf16) = h1r(bf16) @ W2 ----------------------------------

__global__ __launch_bounds__(256, 2) void k_gemm2(const uint* __restrict__ h1ru,
                                                  const float* __restrict__ W2,
                                                  ushort* __restrict__ h2b) {
    __shared__ float xs[128][129];
    __shared__ float Ws[128 * 18];
    int row0 = blockIdx.x * 128;
    int tid = threadIdx.x;

    for (int i = tid; i < 128 * 18; i += 256) Ws[i] = W2[i];
    for (int i = tid; i < 128 * 64; i += 256) {
        int r = i >> 6, c2 = i & 63;
        int gr = row0 + r;
        uint u = (gr < NN) ? h1ru[(size_t)gr * 64 + c2] : 0u;
        xs[r][2 * c2]     = bf_lo(u);
        xs[r][2 * c2 + 1] = bf_hi(u);
    }
    __syncthreads();

    int rl   = tid & 127;
    int half = tid >> 7;
    int j0   = half * 9;
    float acc[9];
#pragma unroll
    for (int j = 0; j < 9; ++j) acc[j] = 0.0f;

#pragma unroll 4
    for (int k = 0; k < 128; ++k) {
        float xv = xs[rl][k];
#pragma unroll
        for (int j = 0; j < 9; ++j)
            acc[j] += xv * Ws[k * 18 + j0 + j];
    }
    int gr = row0 + rl;
    if (gr < NN) {
#pragma unroll
        for (int j = 0; j < 9; ++j) {
            uint ua = __float_as_uint(acc[j]);
            ua += 0x7FFFu + ((ua >> 16) & 1u);
            h2b[(size_t)gr * 18 + j0 + j] = (ushort)(ua >> 16);
        }
    }
}

// ------- agg2 (CSR gather, bf16) + self-loop + bias + log_softmax -----------

__global__ __launch_bounds__(256) void k_agg2(const int* __restrict__ row_start,
                                              const int* __restrict__ csr_src,
                                              const float* __restrict__ dinv,
                                              const uint* __restrict__ h2u,
                                              const float* __restrict__ b2,
                                              float* __restrict__ out) {
    int i = blockIdx.x * 256 + threadIdx.x;
    if (i >= NN) return;
    int r0 = row_start[i], r1 = row_start[i + 1];
    float di = dinv[i];
    float acc[CO];
#pragma unroll
    for (int j = 0; j < CO; ++j) acc[j] = 0.0f;

    for (int e = r0; e < r1; ++e) {
        int s = csr_src[e];
        float w = dinv[s] * di;
        const uint* hr = h2u + (size_t)s * 9;
#pragma unroll
        for (int j = 0; j < 9; ++j) {
            uint u = hr[j];
            acc[2 * j]     += w * bf_lo(u);
            acc[2 * j + 1] += w * bf_hi(u);
        }
    }

    float di2 = di * di;
    const uint* hi = h2u + (size_t)i * 9;
    float m = -1e30f;
#pragma unroll
    for (int j = 0; j < 9; ++j) {
        uint u = hi[j];
        acc[2 * j]     += di2 * bf_lo(u) + b2[2 * j];
        acc[2 * j + 1] += di2 * bf_hi(u) + b2[2 * j + 1];
    }
#pragma unroll
    for (int j = 0; j < CO; ++j) m = fmaxf(m, acc[j]);
    float sum = 0.0f;
#pragma unroll
    for (int j = 0; j < CO; ++j) sum += expf(acc[j] - m);
    float lse = logf(sum);
    float* op = out + (size_t)i * CO;
#pragma unroll
    for (int j = 0; j < CO; ++j) op[j] = acc[j] - m - lse;
}

// ---------------- launch ----------------

extern "C" void kernel_launch(void* const* d_in, const int* in_sizes, int n_in,
                              void* d_out, int out_size, void* d_ws, size_t ws_size,
                              hipStream_t stream) {
    const float* x  = (const float*)d_in[0];
    const int*   ei = (const int*)d_in[1];
    const float* W1 = (const float*)d_in[2];
    const float* b1 = (const float*)d_in[3];
    const float* W2 = (const float*)d_in[4];
    const float* b2 = (const float*)d_in[5];
    float* out = (float*)d_out;

    const int* src = ei;
    const int* dst = ei + NE;

    // workspace layout (~75 MB)
    uint* h1u  = (uint*)d_ws;                        // N*64 uints (bf16 pairs)
    uint* h1ru = h1u + (size_t)NN * 64;              // N*64
    uint* h2u  = h1ru + (size_t)NN * 64;             // N*9
    float* dinv = (float*)(h2u + (size_t)NN * 9);    // N
    int* row_start = (int*)(dinv + NN);              // N+1
    int* csr_src   = row_start + NN + 1;             // E
    uint2* etmp    = (uint2*)(csr_src + NE);         // E records (8B)
    int* bcnt      = (int*)(etmp + NE);              // NBUK
    int* bbase     = bcnt + NBUK;                    // NBUK+1
    int* bcur      = bbase + NBUK + 1;               // NBUK

    hipMemsetAsync(bcnt, 0, NBUK * sizeof(int), stream);

    k_bhist<<<NBB, 256, 0, stream>>>(dst, bcnt);
    k_bscan<<<1, 512, 0, stream>>>(bcnt, bbase, bcur);
    k_bin<<<NBB, 256, 0, stream>>>(src, dst, bcur, etmp);
    k_pass2<<<NBUK, 256, 0, stream>>>(bbase, etmp, row_start, dinv, csr_src);

    k_gemm1<<<(NN + 63) / 64, 256, 0, stream>>>(x, W1, h1u);
    k_agg1<<<(NN + 3) / 4, 256, 0, stream>>>(row_start, csr_src, dinv, h1u, b1, h1ru);
    k_gemm2<<<(NN + 127) / 128, 256, 0, stream>>>(h1ru, W2, (ushort*)h2u);
    k_agg2<<<(NN + 255) / 256, 256, 0, stream>>>(row_start, csr_src, dinv, h2u, b2, out);
}

// Round 5
// 250.198 us; speedup vs baseline: 4.5808x; 1.3497x over previous
//
#include <hip/hip_runtime.h>
#include <math.h>

#define NN 100000
#define NE 1600000
#define CH  128
#define CO  18
#define NPB 256                        // nodes per bucket (dst >> 8)
#define NBUK ((NN + NPB - 1) / NPB)    // 391
#define EPB 4096                       // edges per k_bin block
#define NBB ((NE + EPB - 1) / EPB)     // 391

typedef unsigned int uint;
typedef unsigned short ushort;
typedef float floatx4 __attribute__((ext_vector_type(4)));
typedef short short8 __attribute__((ext_vector_type(8)));
typedef ushort ushort4v __attribute__((ext_vector_type(4)));

// ---- bf16 helpers ----
__device__ __forceinline__ float bf_lo(uint u) { return __uint_as_float(u << 16); }
__device__ __forceinline__ float bf_hi(uint u) { return __uint_as_float(u & 0xFFFF0000u); }
__device__ __forceinline__ ushort f2bf(float f) {
    uint u = __float_as_uint(f);
    u += 0x7FFFu + ((u >> 16) & 1u);        // RNE
    return (ushort)(u >> 16);
}
__device__ __forceinline__ uint pack_bf16(float a, float b) {
    return (uint)f2bf(a) | ((uint)f2bf(b) << 16);
}

// ---------------- binned CSR build ----------------

__global__ __launch_bounds__(256) void k_bhist(const int* __restrict__ dst,
                                               int* __restrict__ bcnt) {
    __shared__ int h[NBUK];
    int tid = threadIdx.x;
    for (int i = tid; i < NBUK; i += 256) h[i] = 0;
    __syncthreads();
    int e0 = blockIdx.x * EPB;
#pragma unroll
    for (int i = 0; i < EPB / 256; ++i) {
        int e = e0 + i * 256 + tid;
        if (e < NE) atomicAdd(&h[dst[e] >> 8], 1);
    }
    __syncthreads();
    for (int i = tid; i < NBUK; i += 256)
        if (h[i]) atomicAdd(&bcnt[i], h[i]);
}

__global__ __launch_bounds__(512) void k_bscan(const int* __restrict__ bcnt,
                                               int* __restrict__ bbase,
                                               int* __restrict__ bcur) {
    __shared__ int s[512];
    int tid = threadIdx.x;
    int c = (tid < NBUK) ? bcnt[tid] : 0;
    s[tid] = c;
    __syncthreads();
    for (int off = 1; off < 512; off <<= 1) {
        int t = (tid >= off) ? s[tid - off] : 0;
        __syncthreads();
        s[tid] += t;
        __syncthreads();
    }
    if (tid < NBUK) {
        int ex = s[tid] - c;
        bbase[tid] = ex;
        bcur[tid] = ex;
    }
    if (tid == NBUK) bbase[NBUK] = NE;
}

__global__ __launch_bounds__(256) void k_bin(const int* __restrict__ src,
                                             const int* __restrict__ dst,
                                             int* __restrict__ bcur,
                                             uint2* __restrict__ etmp) {
    __shared__ int h[NBUK];
    __shared__ int base[NBUK];
    int tid = threadIdx.x;
    for (int i = tid; i < NBUK; i += 256) h[i] = 0;
    __syncthreads();

    int e0 = blockIdx.x * EPB;
    int sv[EPB / 256], dv[EPB / 256];
#pragma unroll
    for (int i = 0; i < EPB / 256; ++i) {
        int e = e0 + i * 256 + tid;
        if (e < NE) {
            sv[i] = src[e];
            dv[i] = dst[e];
            atomicAdd(&h[dv[i] >> 8], 1);
        } else {
            dv[i] = -1;
        }
    }
    __syncthreads();
    for (int i = tid; i < NBUK; i += 256)
        base[i] = h[i] ? atomicAdd(&bcur[i], h[i]) : 0;
    __syncthreads();
    for (int i = tid; i < NBUK; i += 256) h[i] = 0;
    __syncthreads();
#pragma unroll
    for (int i = 0; i < EPB / 256; ++i) {
        if (dv[i] >= 0) {
            int b = dv[i] >> 8;
            int pos = base[b] + atomicAdd(&h[b], 1);
            etmp[pos] = make_uint2((uint)sv[i], (uint)dv[i]);
        }
    }
}

__global__ __launch_bounds__(256) void k_pass2(const int* __restrict__ bbase,
                                               const uint2* __restrict__ etmp,
                                               int* __restrict__ row_start,
                                               float* __restrict__ dinv,
                                               int* __restrict__ csr_src) {
    __shared__ int hist[NPB];
    __shared__ int s[NPB];
    __shared__ int cur[NPB];
    int tid = threadIdx.x;
    int b = blockIdx.x;
    int e0 = bbase[b], e1 = bbase[b + 1];

    hist[tid] = 0;
    __syncthreads();
    for (int e = e0 + tid; e < e1; e += 256)
        atomicAdd(&hist[etmp[e].y & 255], 1);
    __syncthreads();

    int c = hist[tid];
    s[tid] = c;
    __syncthreads();
    for (int off = 1; off < 256; off <<= 1) {
        int t = (tid >= off) ? s[tid - off] : 0;
        __syncthreads();
        s[tid] += t;
        __syncthreads();
    }
    int pfx = s[tid] - c;
    s[tid] = pfx;
    cur[tid] = 0;

    int node = b * NPB + tid;
    if (node < NN) {
        row_start[node] = e0 + pfx;
        dinv[node] = rsqrtf((float)c + 1.0f);
    }
    if (b == NBUK - 1 && tid == 0) row_start[NN] = NE;
    __syncthreads();

    for (int e = e0 + tid; e < e1; e += 256) {
        uint2 r = etmp[e];
        int n = r.y & 255;
        int p = e0 + s[n] + atomicAdd(&cur[n], 1);
        csr_src[p] = (int)r.x;
    }
}

// ------- W1 prep: Wt[n][k] = bf16(W1[k][n]) --------------------------------

__global__ __launch_bounds__(256) void k_wprep(const float* __restrict__ W1,
                                               ushort* __restrict__ Wt) {
    int t = blockIdx.x * 256 + threadIdx.x;   // 64 blocks
    if (t < 128 * 128) {
        int k = t >> 7, n = t & 127;
        Wt[n * 128 + k] = f2bf(W1[t]);
    }
}

// ------- GEMM1 (MFMA): h1(bf16) = x @ W1 -----------------------------------
// Block: 256 thr = 4 waves, tile 128 rows x 128 cols, K=128 (4 steps of 32).
// As[r][k], Bs[n][k] bf16 in LDS with XOR swizzle (idx ^= (r&7)<<3 in ushorts
// = byte^((r&7)<<4)) -> ds_read_b128 fragment reads conflict-free (G4/T2).
// Frag layout (m89-verified): A/B lane l -> row/col l&15, k=(l>>4)*8+i;
// D lane l reg i -> col l&15, row (l>>4)*4+i.

__global__ __launch_bounds__(256, 2) void k_gemm1(const float* __restrict__ x,
                                                  const uint* __restrict__ Wtg,
                                                  ushort* __restrict__ h1s) {
    __shared__ ushort As[128 * 128];
    __shared__ ushort Bs[128 * 128];
    int tid = threadIdx.x;
    int row0 = blockIdx.x * 128;

    // stage Wt (bf16, [n][k]) -> Bs swizzled; uint j = n*64 + ku
    for (int i = 0; i < 32; ++i) {
        int j = i * 256 + tid;
        int n = j >> 6, ku = j & 63;
        int uidx = (n * 64 + ku) ^ ((n & 7) << 2);
        ((uint*)Bs)[uidx] = Wtg[j];
    }
    // stage x rows -> As (fp32 -> bf16), float4 per thread-iter
    for (int i = 0; i < 16; ++i) {
        int flat = i * 256 + tid;            // 4096 float4 groups
        int r = flat >> 5, c4 = flat & 31;
        int gr = row0 + r;
        float4 v = (gr < NN) ? ((const float4*)x)[(size_t)gr * 32 + c4]
                             : make_float4(0.f, 0.f, 0.f, 0.f);
        ushort4v p;
        p.x = f2bf(v.x); p.y = f2bf(v.y); p.z = f2bf(v.z); p.w = f2bf(v.w);
        int idx = (r * 128 + c4 * 4) ^ ((r & 7) << 3);
        *(ushort4v*)&As[idx] = p;
    }
    __syncthreads();

    int lane = tid & 63;
    int wave = tid >> 6;
    int wrow = wave * 32;                     // wave owns 32 rows (2 tiles)
    int lr = lane & 15;
    int lk8 = (lane >> 4) * 8;

    floatx4 acc[2][8];
#pragma unroll
    for (int a = 0; a < 2; ++a)
#pragma unroll
        for (int b = 0; b < 8; ++b) acc[a][b] = (floatx4)(0.0f);

#pragma unroll
    for (int ks = 0; ks < 4; ++ks) {
        int k0 = ks * 32 + lk8;
        int r0r = wrow + lr;
        int r1r = wrow + 16 + lr;
        short8 a0 = *(const short8*)&As[(r0r * 128 + k0) ^ ((r0r & 7) << 3)];
        short8 a1 = *(const short8*)&As[(r1r * 128 + k0) ^ ((r1r & 7) << 3)];
#pragma unroll
        for (int nt = 0; nt < 8; ++nt) {
            int n = nt * 16 + lr;
            short8 bf = *(const short8*)&Bs[(n * 128 + k0) ^ ((n & 7) << 3)];
            acc[0][nt] = __builtin_amdgcn_mfma_f32_16x16x32_bf16(a0, bf, acc[0][nt], 0, 0, 0);
            acc[1][nt] = __builtin_amdgcn_mfma_f32_16x16x32_bf16(a1, bf, acc[1][nt], 0, 0, 0);
        }
    }

    int drow = (lane >> 4) * 4;
#pragma unroll
    for (int rt = 0; rt < 2; ++rt) {
#pragma unroll
        for (int i = 0; i < 4; ++i) {
            int gr = row0 + wrow + rt * 16 + drow + i;
            if (gr < NN) {
                size_t base = (size_t)gr * 128;
#pragma unroll
                for (int nt = 0; nt < 8; ++nt)
                    h1s[base + nt * 16 + lr] = f2bf(acc[rt][nt][i]);
            }
        }
    }
}

// ------- agg1 (CSR gather, bf16 rows) + self-loop + bias + relu -> bf16 -----
// one wave per node, 4-edge unroll for memory-level parallelism

__global__ __launch_bounds__(256) void k_agg1(const int* __restrict__ row_start,
                                              const int* __restrict__ csr_src,
                                              const float* __restrict__ dinv,
                                              const uint* __restrict__ h1u,
                                              const float* __restrict__ b1,
                                              uint* __restrict__ h1ru) {
    int wave = threadIdx.x >> 6;
    int lane = threadIdx.x & 63;
    int i = blockIdx.x * 4 + wave;
    if (i >= NN) return;
    int r0 = row_start[i], r1 = row_start[i + 1];
    float di = dinv[i];
    float ax = 0.0f, ay = 0.0f;

    int j = r0;
    for (; j + 3 < r1; j += 4) {
        int s0 = csr_src[j], s1 = csr_src[j + 1];
        int s2 = csr_src[j + 2], s3 = csr_src[j + 3];
        float w0 = dinv[s0] * di, w1 = dinv[s1] * di;
        float w2 = dinv[s2] * di, w3 = dinv[s3] * di;
        uint u0 = h1u[(size_t)s0 * 64 + lane];
        uint u1 = h1u[(size_t)s1 * 64 + lane];
        uint u2 = h1u[(size_t)s2 * 64 + lane];
        uint u3 = h1u[(size_t)s3 * 64 + lane];
        ax += w0 * bf_lo(u0) + w1 * bf_lo(u1) + w2 * bf_lo(u2) + w3 * bf_lo(u3);
        ay += w0 * bf_hi(u0) + w1 * bf_hi(u1) + w2 * bf_hi(u2) + w3 * bf_hi(u3);
    }
    for (; j < r1; ++j) {
        int s0 = csr_src[j];
        float w0 = dinv[s0] * di;
        uint u0 = h1u[(size_t)s0 * 64 + lane];
        ax += w0 * bf_lo(u0);
        ay += w0 * bf_hi(u0);
    }

    uint us = h1u[(size_t)i * 64 + lane];
    float2 bb = ((const float2*)b1)[lane];
    float di2 = di * di;
    float ox = fmaxf(ax + di2 * bf_lo(us) + bb.x, 0.0f);
    float oy = fmaxf(ay + di2 * bf_hi(us) + bb.y, 0.0f);
    h1ru[(size_t)i * 64 + lane] = pack_bf16(ox, oy);
}

// ------- GEMM2: h2b(bf16) = h1r(bf16) @ W2 ----------------------------------

__global__ __launch_bounds__(256, 2) void k_gemm2(const uint* __restrict__ h1ru,
                                                  const float* __restrict__ W2,
                                                  ushort* __restrict__ h2b) {
    __shared__ float xs[128][129];
    __shared__ float Ws[128 * 18];
    int row0 = blockIdx.x * 128;
    int tid = threadIdx.x;

    for (int i = tid; i < 128 * 18; i += 256) Ws[i] = W2[i];
    for (int i = tid; i < 128 * 64; i += 256) {
        int r = i >> 6, c2 = i & 63;
        int gr = row0 + r;
        uint u = (gr < NN) ? h1ru[(size_t)gr * 64 + c2] : 0u;
        xs[r][2 * c2]     = bf_lo(u);
        xs[r][2 * c2 + 1] = bf_hi(u);
    }
    __syncthreads();

    int rl   = tid & 127;
    int half = tid >> 7;
    int j0   = half * 9;
    float acc[9];
#pragma unroll
    for (int j = 0; j < 9; ++j) acc[j] = 0.0f;

#pragma unroll 4
    for (int k = 0; k < 128; ++k) {
        float xv = xs[rl][k];
#pragma unroll
        for (int j = 0; j < 9; ++j)
            acc[j] += xv * Ws[k * 18 + j0 + j];
    }
    int gr = row0 + rl;
    if (gr < NN) {
#pragma unroll
        for (int j = 0; j < 9; ++j)
            h2b[(size_t)gr * 18 + j0 + j] = f2bf(acc[j]);
    }
}

// ------- agg2 (CSR gather, bf16) + self-loop + bias + log_softmax -----------

__global__ __launch_bounds__(256) void k_agg2(const int* __restrict__ row_start,
                                              const int* __restrict__ csr_src,
                                              const float* __restrict__ dinv,
                                              const uint* __restrict__ h2u,
                                              const float* __restrict__ b2,
                                              float* __restrict__ out) {
    int i = blockIdx.x * 256 + threadIdx.x;
    if (i >= NN) return;
    int r0 = row_start[i], r1 = row_start[i + 1];
    float di = dinv[i];
    float acc[CO];
#pragma unroll
    for (int j = 0; j < CO; ++j) acc[j] = 0.0f;

    for (int e = r0; e < r1; ++e) {
        int s = csr_src[e];
        float w = dinv[s] * di;
        const uint* hr = h2u + (size_t)s * 9;
#pragma unroll
        for (int j = 0; j < 9; ++j) {
            uint u = hr[j];
            acc[2 * j]     += w * bf_lo(u);
            acc[2 * j + 1] += w * bf_hi(u);
        }
    }

    float di2 = di * di;
    const uint* hi = h2u + (size_t)i * 9;
    float m = -1e30f;
#pragma unroll
    for (int j = 0; j < 9; ++j) {
        uint u = hi[j];
        acc[2 * j]     += di2 * bf_lo(u) + b2[2 * j];
        acc[2 * j + 1] += di2 * bf_hi(u) + b2[2 * j + 1];
    }
#pragma unroll
    for (int j = 0; j < CO; ++j) m = fmaxf(m, acc[j]);
    float sum = 0.0f;
#pragma unroll
    for (int j = 0; j < CO; ++j) sum += expf(acc[j] - m);
    float lse = logf(sum);
    float* op = out + (size_t)i * CO;
#pragma unroll
    for (int j = 0; j < CO; ++j) op[j] = acc[j] - m - lse;
}

// ---------------- launch ----------------

extern "C" void kernel_launch(void* const* d_in, const int* in_sizes, int n_in,
                              void* d_out, int out_size, void* d_ws, size_t ws_size,
                              hipStream_t stream) {
    const float* x  = (const float*)d_in[0];
    const int*   ei = (const int*)d_in[1];
    const float* W1 = (const float*)d_in[2];
    const float* b1 = (const float*)d_in[3];
    const float* W2 = (const float*)d_in[4];
    const float* b2 = (const float*)d_in[5];
    float* out = (float*)d_out;

    const int* src = ei;
    const int* dst = ei + NE;

    // workspace layout (~75 MB)
    uint* h1u  = (uint*)d_ws;                        // N*64 uints (bf16 pairs)
    uint* h1ru = h1u + (size_t)NN * 64;              // N*64
    uint* h2u  = h1ru + (size_t)NN * 64;             // N*9
    float* dinv = (float*)(h2u + (size_t)NN * 9);    // N
    int* row_start = (int*)(dinv + NN);              // N+1
    int* csr_src   = row_start + NN + 1;             // E
    uint2* etmp    = (uint2*)(csr_src + NE);         // E records (8B)
    int* bcnt      = (int*)(etmp + NE);              // NBUK
    int* bbase     = bcnt + NBUK;                    // NBUK+1
    int* bcur      = bbase + NBUK + 1;               // NBUK
    ushort* Wt     = (ushort*)(bcur + NBUK);         // 128*128 bf16

    hipMemsetAsync(bcnt, 0, NBUK * sizeof(int), stream);

    k_bhist<<<NBB, 256, 0, stream>>>(dst, bcnt);
    k_bscan<<<1, 512, 0, stream>>>(bcnt, bbase, bcur);
    k_bin<<<NBB, 256, 0, stream>>>(src, dst, bcur, etmp);
    k_pass2<<<NBUK, 256, 0, stream>>>(bbase, etmp, row_start, dinv, csr_src);

    k_wprep<<<64, 256, 0, stream>>>(W1, Wt);
    k_gemm1<<<(NN + 127) / 128, 256, 0, stream>>>(x, (const uint*)Wt, (ushort*)h1u);
    k_agg1<<<(NN + 3) / 4, 256, 0, stream>>>(row_start, csr_src, dinv, h1u, b1, h1ru);
    k_gemm2<<<(NN + 127) / 128, 256, 0, stream>>>(h1ru, W2, (ushort*)h2u);
    k_agg2<<<(NN + 255) / 256, 256, 0, stream>>>(row_start, csr_src, dinv, h2u, b2, out);
}